// Round 1
// baseline (279.105 us; speedup 1.0000x reference)
//
#include <hip/hip_runtime.h>

// CNN_36644660970295: 16 steps of [wrap-pad 1, conv3x3 (1->2ch), +b1, tanh,
// conv1x1 (2->1ch), +b2, relu] on B=32, 512x512 fp32.
// Round 1: one kernel per step, ping-pong d_ws <-> d_out.

#define HH 512
#define WW 512
#define BB 32

__device__ __forceinline__ float tanh_fast(float x) {
    // tanh(x) = 1 - 2/(exp(2x)+1); safe at +/-inf (exp->inf => 1, exp->0 => -1)
    float e = __expf(2.0f * x);
    return 1.0f - 2.0f * __builtin_amdgcn_rcpf(e + 1.0f);
}

__global__ __launch_bounds__(256) void step_kernel(
    const float* __restrict__ in, float* __restrict__ out,
    const float* __restrict__ w1, const float* __restrict__ b1,
    const float* __restrict__ w2, const float* __restrict__ b2)
{
    int idx = blockIdx.x * 256 + threadIdx.x;
    int j = (idx & 127) << 2;            // 0,4,...,508
    int i = (idx >> 7) & 511;            // row
    int b = idx >> 16;                   // image index (idx / (128*512))
    const float* img = in + (size_t)b * (HH * WW);

    int im1 = (i == 0) ? (HH - 1) : (i - 1);
    int ip1 = (i == HH - 1) ? 0 : (i + 1);
    int jm1 = (j == 0) ? (WW - 1) : (j - 1);
    int jp4 = (j == WW - 4) ? 0 : (j + 4);

    // Load 3 rows x 6 cols (wrap at borders)
    float c[3][6];
    {
        const float* r0 = img + im1 * WW;
        const float* r1 = img + i   * WW;
        const float* r2 = img + ip1 * WW;
        float4 v0 = *reinterpret_cast<const float4*>(r0 + j);
        float4 v1 = *reinterpret_cast<const float4*>(r1 + j);
        float4 v2 = *reinterpret_cast<const float4*>(r2 + j);
        c[0][0] = r0[jm1]; c[0][1] = v0.x; c[0][2] = v0.y; c[0][3] = v0.z; c[0][4] = v0.w; c[0][5] = r0[jp4];
        c[1][0] = r1[jm1]; c[1][1] = v1.x; c[1][2] = v1.y; c[1][3] = v1.z; c[1][4] = v1.w; c[1][5] = r1[jp4];
        c[2][0] = r2[jm1]; c[2][1] = v2.x; c[2][2] = v2.y; c[2][3] = v2.z; c[2][4] = v2.w; c[2][5] = r2[jp4];
    }

    // Weights (uniform -> scalar loads, L1-cached)
    float W1[2][3][3];
    #pragma unroll
    for (int ch = 0; ch < 2; ++ch)
        #pragma unroll
        for (int r = 0; r < 3; ++r)
            #pragma unroll
            for (int q = 0; q < 3; ++q)
                W1[ch][r][q] = w1[ch * 9 + r * 3 + q];
    float B1_0 = b1[0], B1_1 = b1[1];
    float W2_0 = w2[0], W2_1 = w2[1];
    float B2   = b2[0];

    float res[4];
    #pragma unroll
    for (int p = 0; p < 4; ++p) {
        float acc0 = B1_0, acc1 = B1_1;
        #pragma unroll
        for (int r = 0; r < 3; ++r) {
            #pragma unroll
            for (int q = 0; q < 3; ++q) {
                float v = c[r][p + q];
                acc0 = fmaf(W1[0][r][q], v, acc0);
                acc1 = fmaf(W1[1][r][q], v, acc1);
            }
        }
        float t0 = tanh_fast(acc0);
        float t1 = tanh_fast(acc1);
        float y  = fmaf(W2_0, t0, fmaf(W2_1, t1, B2));
        res[p] = fmaxf(y, 0.0f);
    }

    *reinterpret_cast<float4*>(out + (size_t)b * (HH * WW) + i * WW + j) =
        make_float4(res[0], res[1], res[2], res[3]);
}

extern "C" void kernel_launch(void* const* d_in, const int* in_sizes, int n_in,
                              void* d_out, int out_size, void* d_ws, size_t ws_size,
                              hipStream_t stream) {
    const float* x  = (const float*)d_in[0];
    const float* w1 = (const float*)d_in[1];
    const float* b1 = (const float*)d_in[2];
    const float* w2 = (const float*)d_in[3];
    const float* b2 = (const float*)d_in[4];
    // steps=16, n=512 are static (setup_inputs) — hardcoded.

    float* A = (float*)d_ws;    // ping
    float* B = (float*)d_out;   // pong (final step lands here)

    const int total_threads = BB * HH * WW / 4;   // 4 px per thread
    dim3 grid(total_threads / 256), block(256);

    // step 1: x -> A
    step_kernel<<<grid, block, 0, stream>>>(x, A, w1, b1, w2, b2);
    const float* src = A;
    // steps 2..16: alternate; odd s writes B(d_out), even s writes A.
    for (int s = 1; s < 16; ++s) {
        float* dst = (s & 1) ? B : A;
        step_kernel<<<grid, block, 0, stream>>>(src, dst, w1, b1, w2, b2);
        src = dst;
    }
}

// Round 2
// 226.906 us; speedup vs baseline: 1.2300x; 1.2300x over previous
//
#include <hip/hip_runtime.h>

// CNN_36644660970295: 16 steps of [wrap-pad 1, conv3x3 (1->2ch), +b1, tanh,
// conv1x1 (2->1ch), +b2, relu] on B=32, 512x512 fp32.
// Round 2: fuse 4 steps per kernel via overlapped tiling in LDS.
// 64x64 output tile + halo 4 => 72x72 LDS tile, ping-pong, shrinking regions.

#define HH 512
#define WW 512
#define BB 32
#define TILE 64
#define HALO 4                  // 4 fused steps
#define BUFW (TILE + 2*HALO)    // 72
#define NPX (BUFW*BUFW)         // 5184

__device__ __forceinline__ float tanh_fast(float x) {
    // tanh(x) = 1 - 2/(exp(2x)+1); safe at +/-inf
    float e = __expf(2.0f * x);
    return 1.0f - 2.0f * __builtin_amdgcn_rcpf(e + 1.0f);
}

__global__ __launch_bounds__(256) void fused4_kernel(
    const float* __restrict__ in, float* __restrict__ out,
    const float* __restrict__ w1, const float* __restrict__ b1,
    const float* __restrict__ w2, const float* __restrict__ b2)
{
    __shared__ float buf[2][NPX];

    const int tid = threadIdx.x;
    const int wg  = blockIdx.x;
    const int tx  = wg & 7;          // 8 tiles across
    const int ty  = (wg >> 3) & 7;   // 8 tiles down
    const int b   = wg >> 6;         // image index
    const float* img = in + (size_t)b * (HH * WW);

    // ---- Global -> LDS (72x72 with wrap halo) ----
    const int base_r = ty * TILE - HALO;
    const int base_c = tx * TILE - HALO;
    for (int idx = tid; idx < NPX; idx += 256) {
        int r = idx / BUFW;
        int c = idx - r * BUFW;
        int gr = (base_r + r) & (HH - 1);
        int gc = (base_c + c) & (WW - 1);
        buf[0][idx] = img[gr * WW + gc];
    }

    // ---- Weights into registers (uniform) ----
    float W1[2][3][3];
    #pragma unroll
    for (int ch = 0; ch < 2; ++ch)
        #pragma unroll
        for (int r = 0; r < 3; ++r)
            #pragma unroll
            for (int q = 0; q < 3; ++q)
                W1[ch][r][q] = w1[ch * 9 + r * 3 + q];
    const float B1_0 = b1[0], B1_1 = b1[1];
    const float W2_0 = w2[0], W2_1 = w2[1];
    const float B2   = b2[0];

    __syncthreads();

    // ---- 4 fused steps, LDS ping-pong, shrinking valid region ----
    #pragma unroll
    for (int s = 0; s < 4; ++s) {
        const float* src = buf[s & 1];
        float*       dst = buf[(s & 1) ^ 1];
        const int lo = s + 1;            // valid output region [lo..hi]^2
        const int hi = (BUFW - 2) - s;   // 70 - s
        const int c0s = lo & ~3;         // 4-aligned strip start
        const int ns  = (hi - c0s) / 4 + 1;   // strips per row (compile-time)
        const int rows = hi - lo + 1;
        const int nwork = rows * ns;

        for (int w = tid; w < nwork; w += 256) {
            int rw = w / ns;                   // const divisor -> magic mul
            int rr = lo + rw;
            int c0 = c0s + 4 * (w - rw * ns);
            const float* r0 = src + (rr - 1) * BUFW;
            const float* r1 = src + rr * BUFW;
            const float* r2 = src + (rr + 1) * BUFW;
            int cm = (c0 == 0) ? 0 : c0 - 1;           // clamped: masked px only
            int cp = (c0 + 4 < BUFW) ? c0 + 4 : BUFW - 1;

            float c0a[6], c1a[6], c2a[6];
            float4 v0 = *reinterpret_cast<const float4*>(r0 + c0);
            float4 v1 = *reinterpret_cast<const float4*>(r1 + c0);
            float4 v2 = *reinterpret_cast<const float4*>(r2 + c0);
            c0a[0] = r0[cm]; c0a[1] = v0.x; c0a[2] = v0.y; c0a[3] = v0.z; c0a[4] = v0.w; c0a[5] = r0[cp];
            c1a[0] = r1[cm]; c1a[1] = v1.x; c1a[2] = v1.y; c1a[3] = v1.z; c1a[4] = v1.w; c1a[5] = r1[cp];
            c2a[0] = r2[cm]; c2a[1] = v2.x; c2a[2] = v2.y; c2a[3] = v2.z; c2a[4] = v2.w; c2a[5] = r2[cp];

            #pragma unroll
            for (int p = 0; p < 4; ++p) {
                float acc0 = B1_0, acc1 = B1_1;
                #pragma unroll
                for (int q = 0; q < 3; ++q) {
                    acc0 = fmaf(W1[0][0][q], c0a[p + q], acc0);
                    acc1 = fmaf(W1[1][0][q], c0a[p + q], acc1);
                    acc0 = fmaf(W1[0][1][q], c1a[p + q], acc0);
                    acc1 = fmaf(W1[1][1][q], c1a[p + q], acc1);
                    acc0 = fmaf(W1[0][2][q], c2a[p + q], acc0);
                    acc1 = fmaf(W1[1][2][q], c2a[p + q], acc1);
                }
                float t0 = tanh_fast(acc0);
                float t1 = tanh_fast(acc1);
                float y  = fmaf(W2_0, t0, fmaf(W2_1, t1, B2));
                y = fmaxf(y, 0.0f);
                int cc = c0 + p;
                if (cc >= lo && cc <= hi)
                    dst[rr * BUFW + cc] = y;
            }
        }
        __syncthreads();
    }

    // ---- LDS -> global (valid [HALO..HALO+63]^2 in buf[0]) ----
    float* og = out + (size_t)b * (HH * WW);
    const int orow = ty * TILE;
    const int ocol = tx * TILE;
    for (int w = tid; w < TILE * (TILE / 4); w += 256) {
        int rr = w >> 4;               // 0..63
        int c4 = (w & 15) << 2;        // 0..60
        float4 v = *reinterpret_cast<const float4*>(
            buf[0] + (rr + HALO) * BUFW + (c4 + HALO));
        *reinterpret_cast<float4*>(og + (size_t)(orow + rr) * WW + ocol + c4) = v;
    }
}

extern "C" void kernel_launch(void* const* d_in, const int* in_sizes, int n_in,
                              void* d_out, int out_size, void* d_ws, size_t ws_size,
                              hipStream_t stream) {
    const float* x  = (const float*)d_in[0];
    const float* w1 = (const float*)d_in[1];
    const float* b1 = (const float*)d_in[2];
    const float* w2 = (const float*)d_in[3];
    const float* b2 = (const float*)d_in[4];

    float* A = (float*)d_ws;    // ping
    float* B = (float*)d_out;   // pong (final group lands here)

    dim3 grid(BB * 8 * 8), block(256);   // 2048 workgroups

    // 4 fused groups of 4 steps each: x->A, A->B, B->A, A->B
    fused4_kernel<<<grid, block, 0, stream>>>(x, A, w1, b1, w2, b2);
    fused4_kernel<<<grid, block, 0, stream>>>(A, B, w1, b1, w2, b2);
    fused4_kernel<<<grid, block, 0, stream>>>(B, A, w1, b1, w2, b2);
    fused4_kernel<<<grid, block, 0, stream>>>(A, B, w1, b1, w2, b2);
}